// Round 10
// baseline (636.953 us; speedup 1.0000x reference)
//
#include <hip/hip_runtime.h>
#include <cfloat>
#include <cmath>

#define TPB 256

typedef _Float16 half8 __attribute__((ext_vector_type(8)));
typedef float floatx16 __attribute__((ext_vector_type(16)));
typedef float floatx4 __attribute__((ext_vector_type(4)));
typedef float floatx2 __attribute__((ext_vector_type(2)));

__device__ __forceinline__ float wave_reduce_sum(float v) {
#pragma unroll
  for (int off = 32; off > 0; off >>= 1) v += __shfl_xor(v, off, 64);
  return v;
}

// ---------------------------------------------------------------------------
// Kernel 0 (fused): ALL input-dependent prep in one launch.
// blocks [0,144): enc conv2 B-frags | [144,208): dec1 frags |
// [208,992): decfc frags | [992,5088): mem frags | [5088,13280): mem norms.
// ---------------------------------------------------------------------------
__global__ __launch_bounds__(64) void prep_all(
    const float* __restrict__ ce_w2, const float* __restrict__ ge_w2,
    const float* __restrict__ d_w1, const float* __restrict__ dfcw,
    const float* __restrict__ memg, float* __restrict__ frags,
    float* __restrict__ dec1frags, float* __restrict__ dfcfrags,
    float* __restrict__ memfrags, float* __restrict__ invn) {
  const int blk = blockIdx.x;
  const int lane = threadIdx.x;

  if (blk < 144) {  // encoder conv2 B-fragments (2-part f16 split)
    const int enc = blk / 72;
    const int frag = blk % 72;
    const int ks = frag >> 2, part = (frag >> 1) & 1, nt = frag & 1;
    const int tap = ks >> 1, half = ks & 1;
    const float* w2 = enc ? ge_w2 : ce_w2;
    const int n = nt * 32 + (lane & 31);
    const int cb = half * 16 + (lane >> 5) * 8;
    half8 out;
#pragma unroll
    for (int j = 0; j < 8; ++j) {
      float v = w2[(n * 32 + cb + j) * 9 + tap];
      _Float16 h = (_Float16)v;
      out[j] = (part == 0) ? h : (_Float16)((v - (float)h) * 4096.f);
    }
    *(half8*)((char*)frags + ((size_t)blk * 64 + lane) * 16) = out;
  } else if (blk < 208) {  // decoder deconv1 B-fragments
    const int b2 = blk - 144;
    const int phase = b2 >> 4, ks = b2 & 15;
    const int pa = phase >> 1, pb = phase & 1;
    const int st = ks >> 2, kk = ks & 3;
    const int s = st >> 1, tt = st & 1;
    const int kg = lane >> 5, n = lane & 31;
    const int tap = (pa + 2 * s) * 4 + (pb + 2 * tt);
    half8 o;
#pragma unroll
    for (int j = 0; j < 8; ++j) {
      int c = kk * 16 + kg * 8 + j;
      o[j] = (_Float16)d_w1[tap * 2048 + c * 32 + n];
    }
    *(half8*)((char*)dec1frags + ((size_t)b2 * 64 + lane) * 16) = o;
  } else if (blk < 992) {  // decfc B-fragments
    const int b2 = blk - 208;
    const int nt = b2 >> 3, ks = b2 & 7;
    const int n = lane & 31, kg = lane >> 5;
    const int j = nt * 32 + n;
    const int px = j >> 6, c = j & 63;
    half8 o;
#pragma unroll
    for (int u = 0; u < 8; ++u)
      o[u] = (_Float16)dfcw[(size_t)(c * 49 + px) * 128 + ks * 16 + kg * 8 + u];
    *(half8*)((char*)dfcfrags + ((size_t)b2 * 64 + lane) * 16) = o;
  } else if (blk < 5088) {  // mem B-fragments (2-part split)
    const int b2 = blk - 992;
    const int slot = b2 & 15;
    const int p = slot >> 3, ks = slot & 7;
    const int T = b2 >> 4;
    const int n = lane & 31, kg = lane >> 5;
    const float* src = memg + (size_t)(T * 32 + n) * 128 + ks * 16 + kg * 8;
    half8 o;
#pragma unroll
    for (int j = 0; j < 8; ++j) {
      float v = src[j];
      _Float16 h = (_Float16)v;
      o[j] = p ? (_Float16)((v - (float)h) * 4096.f) : h;
    }
    *(half8*)((char*)memfrags + ((size_t)b2 * 64 + lane) * 16) = o;
  } else {  // mem row inverse norms (1 row per 64-thread block)
    const int row = blk - 5088;
    const float* r = memg + (size_t)row * 128;
    float a = r[lane], b = r[lane + 64];
    float s = wave_reduce_sum(a * a + b * b);
    if (lane == 0) invn[row] = 1.f / fmaxf(sqrtf(s), 1e-12f);
  }
}

// ---------------------------------------------------------------------------
// Kernel 2: MFMA encoder (v4 — proven 308us, no spill).
// Bands of 7 rows (uniform), 4 blocks/CU, MFMA unit = (M-tile, both nt).
// NOTE: unified VGPR+AGPR file: 64 arch + 64 acc = exactly the 128/wave cap
// at (256,4). Any added register pressure spills catastrophically
// (v6: 2.6GB, v7: 2.2GB scratch). Do not pipeline this loop at source level.
// ---------------------------------------------------------------------------
template <int S, bool CENTER>
__device__ __forceinline__ void encoder_body(
    char* smem, const float* __restrict__ x, const float* __restrict__ w1,
    const float* __restrict__ b1, const float* __restrict__ b2,
    const float* __restrict__ fcw, const float* __restrict__ fcb,
    const float* __restrict__ bfrag, float* __restrict__ zout, int zoff,
    int b) {
  constexpr int SP = S + 2;
  constexpr int NBANDS = S / 7;
  constexpr int NPIX = 9 * SP;
  constexpr int GSTB = NPIX * 16;
  constexpr int PSTB = 4 * GSTB;
  constexpr int LIMIT = 7 * S;
  constexpr int MTB = (LIMIT + 31) / 32;

  char* h1s = smem;
  float* xs = (float*)(smem + 2 * PSTB);
  float* w1s = xs + SP * SP;
  float* featp = w1s + 288;  // [4][64]

  const int t = threadIdx.x;
  const int lane = t & 63;
  const int wv = t >> 6;

  for (int e = t; e < SP * SP; e += TPB) xs[e] = 0.f;
  for (int e = t; e < 288; e += TPB) w1s[e] = w1[e];
  __syncthreads();
  const float* xb = x + (size_t)b * 784 + (CENTER ? (7 * 28 + 7) : 0);
  for (int e = t; e < S * S; e += TPB) {
    int i = e / S, j = e - i * S;
    xs[(i + 1) * SP + (j + 1)] = xb[i * 28 + j];
  }

  float sp0 = 0.f, sp1 = 0.f;
  const float bias0 = b2[lane & 31];
  const float bias1 = b2[32 + (lane & 31)];
  const int gOff = (lane >> 5) * GSTB;
  const char* bgbase = (const char*)bfrag + lane * 16;

#pragma unroll 1
  for (int band = 0; band < NBANDS; ++band) {
    const int b0 = band * 7;

    __syncthreads();
    for (int e = t; e < 4 * NPIX; e += TPB) {
      int g = e / NPIX;
      int pix = e - g * NPIX;
      int lr = pix / SP;
      int cw = pix - lr * SP;
      int gr = b0 - 1 + lr;
      int ebase = g * GSTB + pix * 16;
      half8 hi8 = {}, lo8 = {};
      if (gr >= 0 && gr < S && cw >= 1 && cw <= S) {
        float xv[9];
#pragma unroll
        for (int di = 0; di < 3; ++di)
#pragma unroll
          for (int dj = 0; dj < 3; ++dj)
            xv[di * 3 + dj] = xs[(gr + di) * SP + (cw - 1 + dj)];
#pragma unroll
        for (int u = 0; u < 8; ++u) {
          int ch = g * 8 + u;
          float a = b1[ch];
#pragma unroll
          for (int v = 0; v < 9; ++v) a += xv[v] * w1s[ch * 9 + v];
          a = fmaxf(a, 0.f);
          _Float16 h = (_Float16)a;
          hi8[u] = h;
          lo8[u] = (_Float16)((a - (float)h) * 4096.f);
        }
      }
      *(half8*)(h1s + ebase) = hi8;
      *(half8*)(h1s + PSTB + ebase) = lo8;
    }
    __syncthreads();
#pragma unroll 1
    for (int mt = wv; mt < MTB; mt += 4) {
      floatx16 aH0 = {}, aL0 = {}, aH1 = {}, aL1 = {};
      int px = mt * 32 + (lane & 31);
      px = px < LIMIT ? px : LIMIT - 1;
      const int r = px / S, cc = px - r * S;
      const int pixB = (r * SP + cc) * 16;
#pragma unroll 3
      for (int tap = 0; tap < 9; ++tap) {
        const int di = tap / 3, dj = tap - di * 3;
        const int offT = (di * SP + dj) * 16;
#pragma unroll
        for (int half = 0; half < 2; ++half) {
          const int ks = tap * 2 + half;
          const char* bp = bgbase + ks * 4096;
          const int offA = pixB + offT + gOff + half * (2 * GSTB);
          half8 ah = *(const half8*)(h1s + offA);
          half8 al = *(const half8*)(h1s + PSTB + offA);
          {  // nt = 0
            half8 bh = *(const half8*)(bp);
            half8 bl = *(const half8*)(bp + 2048);
            aH0 = __builtin_amdgcn_mfma_f32_32x32x16_f16(ah, bh, aH0, 0, 0, 0);
            aL0 = __builtin_amdgcn_mfma_f32_32x32x16_f16(ah, bl, aL0, 0, 0, 0);
            aL0 = __builtin_amdgcn_mfma_f32_32x32x16_f16(al, bh, aL0, 0, 0, 0);
          }
          {  // nt = 1
            half8 bh = *(const half8*)(bp + 1024);
            half8 bl = *(const half8*)(bp + 3072);
            aH1 = __builtin_amdgcn_mfma_f32_32x32x16_f16(ah, bh, aH1, 0, 0, 0);
            aL1 = __builtin_amdgcn_mfma_f32_32x32x16_f16(ah, bl, aL1, 0, 0, 0);
            aL1 = __builtin_amdgcn_mfma_f32_32x32x16_f16(al, bh, aL1, 0, 0, 0);
          }
        }
      }
#pragma unroll
      for (int reg = 0; reg < 16; ++reg) {
        int row = (reg & 3) + 8 * (reg >> 2) + 4 * (lane >> 5);
        int p = mt * 32 + row;
        if (p < LIMIT) {
          sp0 += fmaxf(aH0[reg] + aL0[reg] * (1.f / 4096.f) + bias0, 0.f);
          sp1 += fmaxf(aH1[reg] + aL1[reg] * (1.f / 4096.f) + bias1, 0.f);
        }
      }
    }
  }
  sp0 += __shfl_xor(sp0, 32);
  sp1 += __shfl_xor(sp1, 32);
  if (lane < 32) {
    featp[wv * 64 + lane] = sp0;
    featp[wv * 64 + 32 + lane] = sp1;
  }
  __syncthreads();
  if (t < 64)
    featp[t] = (featp[t] + featp[64 + t] + featp[128 + t] + featp[192 + t]) *
               (1.f / (S * S));
  __syncthreads();
  if (t < 64) {
    float s = 0.f;
#pragma unroll
    for (int i = 0; i < 64; ++i) s += featp[i] * fcw[t * 64 + i];
    zout[(size_t)b * 128 + zoff + t] = s + fcb[t];
  }
}

__global__ __launch_bounds__(256, 4) void encoders_fused(
    const float* __restrict__ x, const float* __restrict__ ce_w1,
    const float* __restrict__ ce_b1, const float* __restrict__ ce_b2,
    const float* __restrict__ ce_fcw, const float* __restrict__ ce_fcb,
    const float* __restrict__ ge_w1, const float* __restrict__ ge_b1,
    const float* __restrict__ ge_b2, const float* __restrict__ ge_fcw,
    const float* __restrict__ ge_fcb, const float* __restrict__ frags,
    float* __restrict__ z) {
  // S=28: 2*PSTB(34560) + xs(3600) + w1s(1152) + featp(1024) = 40336 -> 4/CU
  __shared__ __align__(16) char smem[40336];
  if (blockIdx.x < 2048)
    encoder_body<28, false>(smem, x, ge_w1, ge_b1, ge_b2, ge_fcw, ge_fcb,
                            frags + 18432, z, 64, blockIdx.x);
  else
    encoder_body<14, true>(smem, x, ce_w1, ce_b1, ce_b2, ce_fcw, ce_fcb, frags,
                           z, 0, blockIdx.x - 2048);
}

// ---------------------------------------------------------------------------
// Kernel 2b: z normalize + A-fragment build, once per 32-row z-block.
// ---------------------------------------------------------------------------
__global__ __launch_bounds__(256) void zprep_kernel(
    const float* __restrict__ z, float* __restrict__ zfragg) {
  __shared__ __align__(16) float zs[4096];
  __shared__ __align__(16) char zfrag[16384];
  const int t = threadIdx.x;
  const int lane = t & 63;
  const int wv = t >> 6;
  const int rowbase = blockIdx.x * 32;

  for (int e = t; e < 4096; e += TPB) zs[e] = z[(size_t)rowbase * 128 + e];
  __syncthreads();
#pragma unroll
  for (int h = 0; h < 8; ++h) {
    int r = wv * 8 + h;
    float a = zs[r * 128 + lane], b = zs[r * 128 + 64 + lane];
    float s = wave_reduce_sum(a * a + b * b);
    float inv = 1.f / fmaxf(sqrtf(s), 1e-12f);
    zs[r * 128 + lane] = a * inv;
    zs[r * 128 + 64 + lane] = b * inv;
  }
  __syncthreads();
  for (int e = t; e < 4096; e += TPB) {
    int m = e >> 7, c = e & 127;
    float v = zs[m * 128 + c];
    _Float16 h = (_Float16)v;
    _Float16 l = (_Float16)((v - (float)h) * 4096.f);
    int ks = c >> 4, kg = (c >> 3) & 1, j = c & 7;
    int off = (ks * 64 + kg * 32 + m) * 16 + j * 2;
    *(_Float16*)(zfrag + off) = h;
    *(_Float16*)(zfrag + 8192 + off) = l;
  }
  __syncthreads();
  const float4* src = (const float4*)zfrag;
  float4* dst = (float4*)(zfragg + (size_t)blockIdx.x * 4096);
  for (int e = t; e < 1024; e += TPB) dst[e] = src[e];
}

// ---------------------------------------------------------------------------
// Kernel 3a: match via split-f16 MFMA. Deterministic candidate slots (v10),
// qv stride 129 (conflict-free serial scan).
// ---------------------------------------------------------------------------
__global__ __launch_bounds__(256) void match_mfma(
    const float* __restrict__ zfragg, const float* __restrict__ memfrags,
    const float* __restrict__ invn, float* __restrict__ topvw,
    int* __restrict__ topiw) {
  __shared__ __align__(16) float qv[32 * 129];  // 16.5 KB

  const int t = threadIdx.x;
  const int lane = t & 63;
  const int wv = t >> 6;
  const int rowbase = blockIdx.x * 32;
  const int Tbase = blockIdx.y * 16;

  half8 ah[8], al[8];
  {
    const char* zf = (const char*)zfragg + (size_t)blockIdx.x * 16384 +
                     ((lane >> 5) * 32 + (lane & 31)) * 16;
#pragma unroll
    for (int ks = 0; ks < 8; ++ks) {
      ah[ks] = *(const half8*)(zf + ks * 1024);
      al[ks] = *(const half8*)(zf + 8192 + ks * 1024);
    }
  }

  float av[10];
  int ai[10];
#pragma unroll
  for (int i = 0; i < 10; ++i) { av[i] = -FLT_MAX; ai[i] = 0; }

#pragma unroll 1
  for (int round = 0; round < 4; ++round) {
    const int T = Tbase + round * 4 + wv;
    const char* bf = (const char*)memfrags + (size_t)T * 16384 + lane * 16;
    floatx16 acc0 = {}, acc1 = {};
#pragma unroll
    for (int ks = 0; ks < 8; ++ks) {
      half8 bh = *(const half8*)(bf + ks * 1024);
      half8 bl = *(const half8*)(bf + 8192 + ks * 1024);
      acc0 = __builtin_amdgcn_mfma_f32_32x32x16_f16(ah[ks], bh, acc0, 0, 0, 0);
      acc1 = __builtin_amdgcn_mfma_f32_32x32x16_f16(ah[ks], bl, acc1, 0, 0, 0);
      acc1 = __builtin_amdgcn_mfma_f32_32x32x16_f16(al[ks], bh, acc1, 0, 0, 0);
    }
    const int gn = T * 32 + (lane & 31);
    const float iv = invn[gn];
    float* qbase = qv + wv * 32 + (lane & 31);
#pragma unroll
    for (int reg = 0; reg < 16; ++reg) {
      int m = (reg & 3) + 8 * (reg >> 2) + 4 * (lane >> 5);
      qbase[m * 129] = (acc0[reg] + acc1[reg] * (1.f / 4096.f)) * iv;
    }
    __syncthreads();
    if (t < 32) {
      const int gbase = Tbase * 32 + round * 128;
      const float* qr = qv + t * 129;
      for (int k = 0; k < 128; ++k) {
        float v = qr[k];
        if (v > av[9]) {
          int mm = gbase + k;
#pragma unroll
          for (int i = 0; i < 10; ++i) {
            if (v > av[i]) {
              float tv = av[i]; av[i] = v; v = tv;
              int ti = ai[i]; ai[i] = mm; mm = ti;
            }
          }
        }
      }
    }
    __syncthreads();
  }

  if (t < 32) {
    const size_t base = (size_t)(rowbase + t) * 160 + blockIdx.y * 10;
#pragma unroll
    for (int k = 0; k < 10; ++k) {
      topvw[base + k] = av[k];
      topiw[base + k] = ai[k];
    }
  }
}

// ---------------------------------------------------------------------------
// Kernel 4 (fused, v11): merge 16x10 candidates -> top-10 -> softmax ->
// blend into LDS -> decoder FC via f16 MFMA. Replaces match_merge +
// decfc_kernel; deletes one launch and the zmf16 global round-trip.
// Grid (64,7): y-blocks redo the (cheap) merge redundantly for their 32 rows.
// zml row stride = 136 f16 (16B-aligned; 256B stride would be a 32-way bank
// conflict on the a-frag ds_read_b128 — 136 gives ~4-way, once per block).
// Merge scan order identical to v10 -> bit-identical output.
// ---------------------------------------------------------------------------
__global__ __launch_bounds__(256) void merge_decfc(
    const float* __restrict__ topvw, const int* __restrict__ topiw,
    const float* __restrict__ memg, const float* __restrict__ fcb,
    const float* __restrict__ dfcfrags, _Float16* __restrict__ d0f16) {
  __shared__ float topw[32][10];
  __shared__ int topidx[32][10];
  __shared__ __align__(16) _Float16 zml[32 * 136];

  const int t = threadIdx.x;
  const int lane = t & 63;
  const int wv = t >> 6;
  const int r0 = blockIdx.x * 32;
  const int ntbase = blockIdx.y * 14;

  if (t < 32) {
    float av[10];
    int ai[10];
#pragma unroll
    for (int i = 0; i < 10; ++i) { av[i] = -FLT_MAX; ai[i] = 0; }
    const size_t base = (size_t)(r0 + t) * 160;
    for (int c = 0; c < 160; ++c) {
      float v = topvw[base + c];
      int m = topiw[base + c];
      if (v > av[9]) {
#pragma unroll
        for (int i = 0; i < 10; ++i) {
          if (v > av[i]) {
            float tv = av[i]; av[i] = v; v = tv;
            int ti = ai[i]; ai[i] = m; m = ti;
          }
        }
      }
    }
    float e_[10], s = 0.f;
#pragma unroll
    for (int k = 0; k < 10; ++k) { e_[k] = expf(av[k]); s += e_[k]; }
    float inv = 1.f / s;
#pragma unroll
    for (int k = 0; k < 10; ++k) { topw[t][k] = e_[k] * inv; topidx[t][k] = ai[k]; }
  }
  __syncthreads();
  for (int e = t; e < 4096; e += TPB) {
    int r = e >> 7, d = e & 127;
    float o = 0.f;
#pragma unroll
    for (int k = 0; k < 10; ++k)
      o += topw[r][k] * memg[(size_t)topidx[r][k] * 128 + d];
    zml[r * 136 + d] = (_Float16)o;
  }
  __syncthreads();

  half8 a[8];
  {
    const _Float16* ap = zml + (lane & 31) * 136 + (lane >> 5) * 8;
#pragma unroll
    for (int ks = 0; ks < 8; ++ks) a[ks] = *(const half8*)(ap + ks * 16);
  }
  const char* fb = (const char*)dfcfrags + lane * 16;

  for (int nt = ntbase + wv; nt < ntbase + 14; nt += 4) {
    half8 bfr[8];
    const char* p = fb + (size_t)nt * 8192;
#pragma unroll
    for (int ks = 0; ks < 8; ++ks) bfr[ks] = *(const half8*)(p + ks * 1024);
    floatx16 acc = {};
#pragma unroll
    for (int ks = 0; ks < 8; ++ks)
      acc = __builtin_amdgcn_mfma_f32_32x32x16_f16(a[ks], bfr[ks], acc, 0, 0, 0);
    const int col = nt * 32 + (lane & 31);
    const int px = col >> 6, c = col & 63;
    const float bias = fcb[c * 49 + px];
#pragma unroll
    for (int reg = 0; reg < 16; ++reg) {
      int row = (reg & 3) + 8 * (reg >> 2) + 4 * (lane >> 5);
      d0f16[((size_t)(r0 + row) * 49 + px) * 64 + c] = (_Float16)(acc[reg] + bias);
    }
  }
}

// ---------------------------------------------------------------------------
// Kernel 5: decoder — deconv1 + conv2 via f16 MFMA; deconv2 packed floatx2.
// ---------------------------------------------------------------------------
__global__ __launch_bounds__(256) void decoder_kernel(
    const _Float16* __restrict__ d0f16, const float* __restrict__ b1,
    const float* __restrict__ w2, const float* __restrict__ b2,
    const float* __restrict__ w3, const float* __restrict__ b3,
    const float* __restrict__ w4, const float* __restrict__ b4,
    const float* __restrict__ dec1frags, float* __restrict__ out) {
  __shared__ __align__(16) char dsm[39488];
  char* d0f = dsm;
  float* d2 = (float*)dsm;
  char* d1f = dsm + 12608;
  char* w2s = dsm + 28992;
  float* d3 = (float*)(dsm + 12608);  // [8][28*30] = 26880 B

  const int b = blockIdx.x;
  const int t = threadIdx.x;
  const int lane = t & 63;
  const int wv = t >> 6;

  for (int e = t; e < 648; e += TPB) {
    int g = e / 81, pix = e - g * 81;
    int ih = pix / 9 - 1, iw = pix % 9 - 1;
    half8 hv = {};
    if (ih >= 0 && ih < 7 && iw >= 0 && iw < 7)
      hv = *(const half8*)(d0f16 + ((size_t)b * 49 + ih * 7 + iw) * 64 + g * 8);
    *(half8*)(d0f + e * 16) = hv;
  }
  for (int e = t; e < 576; e += TPB) {
    int tau = e / 64, l = e - tau * 64;
    int n = l & 15, kq = l >> 4;
    half8 v;
#pragma unroll
    for (int u = 0; u < 8; ++u)
      v[u] = (_Float16)w2[(n * 32 + kq * 8 + u) * 9 + tau];
    *(half8*)(w2s + e * 16) = v;
  }
  for (int e = t; e < 1024; e += TPB)
    *(float4*)(d1f + e * 16) = make_float4(0.f, 0.f, 0.f, 0.f);
  __syncthreads();

  {
    const int pa = wv >> 1, pb = wv & 1;
    const int kg = lane >> 5, o = lane & 31;
    const char* bg = (const char*)dec1frags + wv * 16384 + lane * 16;
    int pxa[2][4];
#pragma unroll
    for (int im = 0; im < 2; ++im) {
      int px = im * 32 + o;
      px = px < 49 ? px : 48;
      int i = px / 7, j2 = px - i * 7;
#pragma unroll
      for (int st = 0; st < 4; ++st) {
        int s = st >> 1, tt = st & 1;
        pxa[im][st] = ((i + pa + s) * 9 + (j2 + pb + tt)) * 16;
      }
    }
    floatx16 acc0 = {}, acc1 = {};
    half8 nb = *(const half8*)(bg);
#pragma unroll
    for (int ks = 0; ks < 16; ++ks) {
      half8 bf = nb;
      if (ks < 15) nb = *(const half8*)(bg + (ks + 1) * 1024);
      const int gbase = (((ks & 3) * 2 + kg) * 81) * 16;
      half8 a0 = *(const half8*)(d0f + gbase + pxa[0][ks >> 2]);
      half8 a1 = *(const half8*)(d0f + gbase + pxa[1][ks >> 2]);
      acc0 = __builtin_amdgcn_mfma_f32_32x32x16_f16(a0, bf, acc0, 0, 0, 0);
      acc1 = __builtin_amdgcn_mfma_f32_32x32x16_f16(a1, bf, acc1, 0, 0, 0);
    }
    const float bias = b1[o];
    char* dst = d1f + (o >> 3) * 4096 + (o & 7) * 2;
#pragma unroll
    for (int im = 0; im < 2; ++im) {
      const floatx16& ac = im ? acc1 : acc0;
#pragma unroll
      for (int reg = 0; reg < 16; ++reg) {
        int row = (reg & 3) + 8 * (reg >> 2) + 4 * kg;
        int px = im * 32 + row;
        if (px < 49) {
          int i = px / 7, j2 = px - i * 7;
          int p = 2 * i + pa, q = 2 * j2 + pb;
          *(_Float16*)(dst + ((p + 1) * 16 + (q + 1)) * 16) =
              (_Float16)fmaxf(ac[reg] + bias, 0.f);
        }
      }
    }
  }
  __syncthreads();

  {
    const int m = lane & 15, kq = lane >> 4;
    half8 bq[9];
#pragma unroll
    for (int tau = 0; tau < 9; ++tau)
      bq[tau] = *(const half8*)(w2s + (tau * 64 + lane) * 16);
    for (int mt = wv; mt < 13; mt += 4) {
      int px = mt * 16 + m;
      px = px < 196 ? px : 195;
      const int p = px / 14, q = px - (px / 14) * 14;
      floatx4 acc = {};
#pragma unroll
      for (int tau = 0; tau < 9; ++tau) {
        const int dp = tau / 3, dq = tau - dp * 3;
        half8 av =
            *(const half8*)(d1f + (kq * 256 + (p + dp) * 16 + (q + dq)) * 16);
        acc = __builtin_amdgcn_mfma_f32_16x16x32_f16(av, bq[tau], acc, 0, 0, 0);
      }
      const int o = lane & 15;
      const float bias = b2[o];
#pragma unroll
      for (int reg = 0; reg < 4; ++reg) {
        int row = (lane >> 4) * 4 + reg;
        int opx = mt * 16 + row;
        if (opx < 196) d2[o * 197 + opx] = fmaxf(acc[reg] + bias, 0.f);
      }
    }
  }
  __syncthreads();
  for (int e = t; e < 6720; e += TPB) d3[e] = 0.f;
  __syncthreads();

  {
    const int ph = __builtin_amdgcn_readfirstlane(t >> 6);
    const int pa = ph >> 1, pb = ph & 1;
    const int tb = pa * 4 + pb;
    const floatx2* wA2 = (const floatx2*)(w3 + (size_t)tb * 128);
    const floatx2* wB2 = (const floatx2*)(w3 + (size_t)(tb + 2) * 128);
    const floatx2* wC2 = (const floatx2*)(w3 + (size_t)(tb + 8) * 128);
    const floatx2* wD2 = (const floatx2*)(w3 + (size_t)(tb + 10) * 128);
#pragma unroll 1
    for (int k = 0; k < 4; ++k) {
      const int px = lane + 64 * k;
      const int cpx = px < 196 ? px : 195;
      const int i = cpx / 14, j = cpx % 14;
      int ih[2], iw[2];
      float mh[2], mw[2];
#pragma unroll
      for (int s = 0; s < 2; ++s) {
        int v = i + pa + s - 1;
        mh[s] = (v >= 0 && v <= 13) ? 1.f : 0.f;
        ih[s] = v < 0 ? 0 : (v > 13 ? 13 : v);
        int u = j + pb + s - 1;
        mw[s] = (u >= 0 && u <= 13) ? 1.f : 0.f;
        iw[s] = u < 0 ? 0 : (u > 13 ? 13 : u);
      }
      const float m00 = mh[0] * mw[0], m01 = mh[0] * mw[1];
      const float m10 = mh[1] * mw[0], m11 = mh[1] * mw[1];
      floatx2 acc2[4];
#pragma unroll
      for (int o2 = 0; o2 < 4; ++o2) {
        acc2[o2][0] = b3[2 * o2];
        acc2[o2][1] = b3[2 * o2 + 1];
      }
#pragma unroll 2
      for (int c = 0; c < 16; ++c) {
        const float a00 = d2[c * 197 + ih[0] * 14 + iw[0]] * m00;
        const float a01 = d2[c * 197 + ih[0] * 14 + iw[1]] * m01;
        const float a10 = d2[c * 197 + ih[1] * 14 + iw[0]] * m10;
        const float a11 = d2[c * 197 + ih[1] * 14 + iw[1]] * m11;
        const int wb2 = c * 4;
#pragma unroll
        for (int o2 = 0; o2 < 4; ++o2)
          acc2[o2] += a00 * wA2[wb2 + o2] + a01 * wB2[wb2 + o2] +
                      a10 * wC2[wb2 + o2] + a11 * wD2[wb2 + o2];
      }
      if (px < 196) {
        const int p = 2 * i + pa, q = 2 * j + pb;
        const int widx = p * 30 + (q + 1);
#pragma unroll
        for (int oo = 0; oo < 8; ++oo)
          d3[oo * 840 + widx] = fmaxf(acc2[oo >> 1][oo & 1], 0.f);
      }
    }
  }
  __syncthreads();

  for (int e = t; e < 784; e += TPB) {
    int p = e / 28, q = e - p * 28;
    float a = b4[0];
#pragma unroll
    for (int di = 0; di < 3; ++di) {
      const int rr = p + di - 1;
      if (rr >= 0 && rr < 28) {
#pragma unroll
        for (int c = 0; c < 8; ++c) {
          const float* bp = &d3[c * 840 + rr * 30 + q];
#pragma unroll
          for (int dj = 0; dj < 3; ++dj)
            a += bp[dj] * w4[c * 9 + di * 3 + dj];
        }
      }
    }
    out[(size_t)b * 784 + e] = a;
  }
}

// ---------------------------------------------------------------------------
extern "C" void kernel_launch(void* const* d_in, const int* in_sizes, int n_in,
                              void* d_out, int out_size, void* d_ws,
                              size_t ws_size, hipStream_t stream) {
  const float* x      = (const float*)d_in[0];
  const float* ce_w1  = (const float*)d_in[1];
  const float* ce_b1  = (const float*)d_in[2];
  const float* ce_w2  = (const float*)d_in[3];
  const float* ce_b2  = (const float*)d_in[4];
  const float* ce_fcw = (const float*)d_in[5];
  const float* ce_fcb = (const float*)d_in[6];
  const float* ge_w1  = (const float*)d_in[7];
  const float* ge_b1  = (const float*)d_in[8];
  const float* ge_w2  = (const float*)d_in[9];
  const float* ge_b2  = (const float*)d_in[10];
  const float* ge_fcw = (const float*)d_in[11];
  const float* ge_fcb = (const float*)d_in[12];
  const float* memg   = (const float*)d_in[13];
  const float* dfcw   = (const float*)d_in[14];
  const float* dfcb   = (const float*)d_in[15];
  const float* d_w1   = (const float*)d_in[16];
  const float* d_b1   = (const float*)d_in[17];
  const float* d_w2   = (const float*)d_in[18];
  const float* d_b2   = (const float*)d_in[19];
  const float* d_w3   = (const float*)d_in[20];
  const float* d_b3   = (const float*)d_in[21];
  const float* d_w4   = (const float*)d_in[22];
  const float* d_b4   = (const float*)d_in[23];
  float* outp = (float*)d_out;

  float*     ws        = (float*)d_ws;
  float*     z         = ws;
  float*     invn      = ws + 262144 + 131072;
  float*     frags     = invn + 8192;
  float*     dec1frags = frags + 36864;
  float*     dfcfrags  = dec1frags + 16384;
  float*     memfrags  = dfcfrags + 200704;
  float*     tailbase  = memfrags + 1048576;
  float*     topvw     = tailbase;
  int*       topiw     = (int*)(tailbase + 327680);
  float*     zfragg    = tailbase + 655360;
  _Float16*  d0f16     = (_Float16*)(ws + 262144);  // reuse zmf16 slot (bigger: 131072 floats >= 3.2M f16? no) 

  // d0f16 needs 2048*49*64 f16 = 12.25 MB; keep it in the tail region as
  // before (sequential with topv/topi/zfragg usage is over by then is NOT
  // true — merge_decfc reads topvw/topiw while writing d0f16, so place
  // d0f16 AFTER zfragg.
  d0f16 = (_Float16*)(zfragg + 262144);

  prep_all<<<13280, 64, 0, stream>>>(ce_w2, ge_w2, d_w1, dfcw, memg, frags,
                                     dec1frags, dfcfrags, memfrags, invn);
  encoders_fused<<<4096, TPB, 0, stream>>>(x, ce_w1, ce_b1, ce_b2, ce_fcw,
                                           ce_fcb, ge_w1, ge_b1, ge_b2, ge_fcw,
                                           ge_fcb, frags, z);
  zprep_kernel<<<64, TPB, 0, stream>>>(z, zfragg);
  match_mfma<<<dim3(64, 16), TPB, 0, stream>>>(zfragg, memfrags, invn, topvw,
                                               topiw);
  merge_decfc<<<dim3(64, 7), TPB, 0, stream>>>(topvw, topiw, memg, dfcb,
                                               dfcfrags, d0f16);
  decoder_kernel<<<2048, TPB, 0, stream>>>(d0f16, d_b1, d_w2, d_b2, d_w3, d_b3,
                                           d_w4, d_b4, dec1frags, outp);
}